// Round 1
// baseline (45.270 us; speedup 1.0000x reference)
//
#include <hip/hip_runtime.h>

// Problem constants (match setup_inputs; harness always uses these)
constexpr int H  = 2048, W = 4096, HG = 16, WG = 32, BS = 128;
constexpr int S  = 2, Hs = H / S, Ws = W / S;
constexpr int TILE_R = 32, TILE_C = 64;   // tile in m-space (subsampled)
constexpr int LMAX = 1536;                // max rects_m entries (2*Nc+Np)

// ---------------- K0: per-box derived values ----------------
__global__ void k_prep(const float* __restrict__ bc, const float* __restrict__ bp,
                       int Nc, int Np,
                       int* __restrict__ cc, int* __restrict__ cp,
                       int* __restrict__ gc, int* __restrict__ gp,
                       int* __restrict__ mprev)
{
    int t = blockIdx.x * blockDim.x + threadIdx.x;
    if (t < Nc) {
        float x1 = bc[t*5+0], y1 = bc[t*5+1], x2 = bc[t*5+2], y2 = bc[t*5+3];
        ((int4*)cc)[t] = make_int4((int)(x1*0.5f), (int)(y1*0.5f),
                                   (int)(x2*0.5f), (int)(y2*0.5f));
        int ix1=(int)x1, iy1=(int)y1, ix2=(int)x2, iy2=(int)y2;
        ((int4*)gc)[t] = make_int4(ix1/BS, iy1/BS, (ix2-1)/BS, (iy2-1)/BS);
    }
    if (t < Np) {
        float x1 = bp[t*5+0], y1 = bp[t*5+1], x2 = bp[t*5+2], y2 = bp[t*5+3];
        ((int4*)cp)[t] = make_int4((int)(x1*0.5f), (int)(y1*0.5f),
                                   (int)(x2*0.5f), (int)(y2*0.5f));
        int ix1=(int)x1, iy1=(int)y1, ix2=(int)x2, iy2=(int)y2;
        ((int4*)gp)[t] = make_int4(ix1/BS, iy1/BS, (ix2-1)/BS, (iy2-1)/BS);
        mprev[t] = 0;
    }
}

// ---------------- K1: per-curr-box IoU argmax (one wave per box) ----------------
__global__ __launch_bounds__(64) void k_iou(
    const int* __restrict__ cc, const int* __restrict__ cp,
    const int* __restrict__ gc, const int* __restrict__ gp,
    int Nc, int Np,
    int* __restrict__ best_j, int* __restrict__ matched,
    float* __restrict__ ig, int* __restrict__ wrect, int* __restrict__ mprev)
{
    int i = blockIdx.x;
    int lane = threadIdx.x;
    int4 c = ((const int4*)cc)[i];
    float ax1 = (float)c.x, ay1 = (float)c.y, ax2 = (float)c.z, ay2 = (float)c.w;
    float areaA = (ax2 - ax1) * (ay2 - ay1);
    float bi = -1.0f; int bj = 0x7fffffff;
    for (int j = lane; j < Np; j += 64) {
        int4 p = ((const int4*)cp)[j];
        float bx1 = (float)p.x, by1 = (float)p.y, bx2 = (float)p.z, by2 = (float)p.w;
        float ix1 = fmaxf(ax1, bx1), iy1 = fmaxf(ay1, by1);
        float ix2 = fminf(ax2, bx2), iy2 = fminf(ay2, by2);
        float inter = fmaxf(ix2 - ix1, 0.0f) * fmaxf(iy2 - iy1, 0.0f);
        float areaB = (bx2 - bx1) * (by2 - by1);
        float iou = inter / (areaA + areaB - inter);
        if (iou > bi || (iou == bi && j < bj)) { bi = iou; bj = j; }
    }
    // lexicographic argmax reduce (max iou, tie -> smaller j == numpy first-index)
    for (int off = 32; off; off >>= 1) {
        float oi = __shfl_xor(bi, off);
        int   oj = __shfl_xor(bj, off);
        if (oi > bi || (oi == bi && oj < bj)) { bi = oi; bj = oj; }
    }
    if (lane == 0) {
        int m = bi > 0.0f;
        best_j[i] = bj; matched[i] = m; ig[i] = 1.0f - bi;
        int4 g = ((const int4*)gc)[i];
        int4 wr = g;
        if (m) {
            int4 pj = ((const int4*)gp)[bj];
            wr.x = min(g.x, pj.x); wr.y = min(g.y, pj.y);
            wr.z = max(g.z, pj.z); wr.w = max(g.w, pj.w);
            mprev[bj] = 1;   // same value from all writers: deterministic
        }
        ((int4*)wrect)[i] = wr;
    }
}

// ---------------- K2: isolated + val_c (one wave per box) ----------------
__global__ __launch_bounds__(64) void k_isolated(
    const float* __restrict__ bc,
    const int* __restrict__ gc, const int* __restrict__ gp,
    const int* __restrict__ best_j, const int* __restrict__ matched,
    int Nc, int Np, float* __restrict__ val_c)
{
    int i = blockIdx.x, lane = threadIdx.x;
    int4 g = ((const int4*)gc)[i];
    int m = matched[i];
    int bj = best_j[i];
    int4 pj = ((const int4*)gp)[bj];
    bool bad = false;
    int NT = Nc + Np;
    for (int k = lane; k < NT; k += 64) {
        int4 a = (k < Nc) ? ((const int4*)gc)[k] : ((const int4*)gp)[k - Nc];
        bool ov = (g.x <= a.z) && (a.x <= g.z) && (g.y <= a.w) && (a.y <= g.w);
        if (m) ov = ov || ((pj.x <= a.z) && (a.x <= pj.z) && (pj.y <= a.w) && (a.y <= pj.w));
        bool excl = (k == i) || (m && k == Nc + bj);
        bad |= (ov && !excl);
    }
    bool anybad = __any(bad);
    if (lane == 0) {
        int iy1 = (int)bc[i*5+1], iy2 = (int)bc[i*5+3];
        float sc = bc[i*5+4];
        bool big = (iy2 - iy1) >= 100;
        val_c[i] = (!anybad && big && sc >= 0.7f) ? 2.0f : 1.0f;
    }
}

// ---------------- K3: build combined mask-rect list ----------------
__global__ void k_prepmask(const float* __restrict__ bc, const float* __restrict__ bp,
    const int* __restrict__ cc, const int* __restrict__ cp,
    const int* __restrict__ best_j, const int* __restrict__ matched,
    const int* __restrict__ mprev, const float* __restrict__ ig,
    int Nc, int Np, int* __restrict__ rm, float* __restrict__ wm)
{
    int r = blockIdx.x * blockDim.x + threadIdx.x;
    int NT = Nc + Nc + Np;
    if (r >= NT) return;
    int4 rect; float w;
    if (r < Nc) {
        rect = ((const int4*)cc)[r];
        w = ig[r] * bc[r*5+4];
    } else if (r < 2*Nc) {
        int i = r - Nc;
        int bj = best_j[i];
        rect = ((const int4*)cp)[bj];
        w = matched[i] ? ig[i] * bp[bj*5+4] : 0.0f;
    } else {
        int j = r - 2*Nc;
        rect = ((const int4*)cp)[j];
        w = mprev[j] ? 0.0f : bp[j*5+4];
    }
    ((int4*)rm)[r] = rect;
    wm[r] = w;
}

// ---------------- K4: grid_ig (one wave per 16x32 cell) ----------------
__global__ __launch_bounds__(256) void k_grid(
    const int* __restrict__ wrect, const int* __restrict__ gp,
    const float* __restrict__ val_c, const int* __restrict__ mprev,
    int Nc, int Np, float* __restrict__ outg)
{
    int wid  = (int)(blockIdx.x * blockDim.x + threadIdx.x) >> 6;
    int lane = threadIdx.x & 63;
    if (wid >= HG * WG) return;
    int y = wid / WG, x = wid % WG;
    int last = -1;
    int NT = Nc + Np;
    for (int r = lane; r < NT; r += 64) {
        int4 q; bool act;
        if (r < Nc) { q = ((const int4*)wrect)[r]; act = true; }
        else        { int j = r - Nc; q = ((const int4*)gp)[j]; act = !mprev[j]; }
        if (act && x >= q.x && x <= q.z && y >= q.y && y <= q.w) last = r;  // r increasing
    }
    for (int off = 32; off; off >>= 1) last = max(last, __shfl_xor(last, off));
    if (lane == 0) outg[wid] = (last >= 0) ? (last < Nc ? val_c[last] : 1.0f) : 0.0f;
}

// ---------------- K5: rasterize mask with per-tile rect culling ----------------
__global__ __launch_bounds__(256) void k_mask(
    const int* __restrict__ rm, const float* __restrict__ wm, int NR,
    float* __restrict__ out)
{
    __shared__ int Lx0[LMAX], Ly0[LMAX], Lx1[LMAX], Ly1[LMAX];
    __shared__ float Lw[LMAX];
    __shared__ int cnt;
    if (threadIdx.x == 0) cnt = 0;
    __syncthreads();
    int by = blockIdx.y * TILE_R;   // m-space row origin
    int bx = blockIdx.x * TILE_C;   // m-space col origin
    for (int r = threadIdx.x; r < NR; r += 256) {
        int4 q = ((const int4*)rm)[r];
        float w = wm[r];
        // half-open rect [q.x,q.z) x [q.y,q.w) vs tile
        if (w > 0.0f && q.x < bx + TILE_C && q.z > bx && q.y < by + TILE_R && q.w > by) {
            int idx = atomicAdd(&cnt, 1);
            Lx0[idx] = q.x; Ly0[idx] = q.y; Lx1[idx] = q.z; Ly1[idx] = q.w; Lw[idx] = w;
        }
    }
    __syncthreads();
    int n = cnt;
    int tx = threadIdx.x & 31;   // 32 col-groups * 2 cells
    int ty = threadIdx.x >> 5;   // 8 row-groups * 4 rows
    int c0 = bx + tx * 2;
    int r0 = by + ty * 4;
    float mv[4][2];
    #pragma unroll
    for (int rr = 0; rr < 4; rr++) { mv[rr][0] = 0.0f; mv[rr][1] = 0.0f; }
    for (int k = 0; k < n; k++) {
        int qx0 = Lx0[k], qy0 = Ly0[k], qx1 = Lx1[k], qy1 = Ly1[k];  // broadcast LDS reads
        float w = Lw[k];
        bool cx0 = (c0     >= qx0) && (c0     < qx1);
        bool cx1 = (c0 + 1 >= qx0) && (c0 + 1 < qx1);
        #pragma unroll
        for (int rr = 0; rr < 4; rr++) {
            int y = r0 + rr;
            bool cy = (y >= qy0) && (y < qy1);
            if (cy && cx0) mv[rr][0] = fmaxf(mv[rr][0], w);
            if (cy && cx1) mv[rr][1] = fmaxf(mv[rr][1], w);
        }
    }
    // 2x2 upsampled store: each m-cell -> 2x2 output pixels; float4 = 2 cells/row
    #pragma unroll
    for (int rr = 0; rr < 4; rr++) {
        int y = r0 + rr;
        float4 v = make_float4(mv[rr][0], mv[rr][0], mv[rr][1], mv[rr][1]);
        *(float4*)&out[(size_t)(2*y)     * W + 2*c0] = v;
        *(float4*)&out[(size_t)(2*y + 1) * W + 2*c0] = v;
    }
}

extern "C" void kernel_launch(void* const* d_in, const int* in_sizes, int n_in,
                              void* d_out, int out_size, void* d_ws, size_t ws_size,
                              hipStream_t stream)
{
    const float* bc = (const float*)d_in[0];
    const float* bp = (const float*)d_in[1];
    int Nc = in_sizes[0] / 5;
    int Np = in_sizes[1] / 5;
    float* out = (float*)d_out;

    // workspace carve (all 16B-aligned for Nc,Np multiples of 4)
    int* w = (int*)d_ws;
    int* cc      = w;           w += Nc * 4;
    int* cp      = w;           w += Np * 4;
    int* gc      = w;           w += Nc * 4;
    int* gp      = w;           w += Np * 4;
    int* wrect   = w;           w += Nc * 4;
    int* best_j  = w;           w += Nc;
    int* matched = w;           w += Nc;
    float* ig    = (float*)w;   w += Nc;
    float* val_c = (float*)w;   w += Nc;
    int* mprev   = w;           w += Np;
    int* rm      = w;           w += (2*Nc + Np) * 4;
    float* wm    = (float*)w;   w += (2*Nc + Np);

    int nprep = Nc > Np ? Nc : Np;
    k_prep<<<(nprep + 255)/256, 256, 0, stream>>>(bc, bp, Nc, Np, cc, cp, gc, gp, mprev);
    k_iou<<<Nc, 64, 0, stream>>>(cc, cp, gc, gp, Nc, Np, best_j, matched, ig, wrect, mprev);
    k_isolated<<<Nc, 64, 0, stream>>>(bc, gc, gp, best_j, matched, Nc, Np, val_c);
    k_prepmask<<<(2*Nc + Np + 255)/256, 256, 0, stream>>>(bc, bp, cc, cp, best_j, matched,
                                                          mprev, ig, Nc, Np, rm, wm);
    k_grid<<<(HG*WG*64 + 255)/256, 256, 0, stream>>>(wrect, gp, val_c, mprev, Nc, Np,
                                                     out + (size_t)H * W);
    dim3 gmask(Ws / TILE_C, Hs / TILE_R);
    k_mask<<<gmask, 256, 0, stream>>>(rm, wm, 2*Nc + Np, out);
}

// Round 2
// 27.656 us; speedup vs baseline: 1.6369x; 1.6369x over previous
//
#include <hip/hip_runtime.h>

constexpr int H  = 2048, W = 4096, HG = 16, WG = 32, BS = 128;
constexpr int S  = 2, Hs = H / S, Ws = W / S;
constexpr int TILE_R = 32, TILE_C = 64;   // tile in m-space (subsampled)
constexpr int LMAX = 1536;                // max rects_m entries (2*Nc+Np)

// ---------------- K1: fused match/isolated/val_c/wrect/rm-wm (one wave per curr box) ----
__global__ __launch_bounds__(64) void k_match(
    const float* __restrict__ bc, const float* __restrict__ bp,
    int Nc, int Np,
    int* __restrict__ wrect, float* __restrict__ val_c,
    int* __restrict__ bj_matched,
    int* __restrict__ rm, float* __restrict__ wm)
{
    int i = blockIdx.x, lane = threadIdx.x;
    float x1 = bc[i*5+0], y1 = bc[i*5+1], x2 = bc[i*5+2], y2 = bc[i*5+3], sc = bc[i*5+4];
    // cc rect (subsampled coords) as exact small-int floats
    float ax1 = (float)(int)(x1*0.5f), ay1 = (float)(int)(y1*0.5f);
    float ax2 = (float)(int)(x2*0.5f), ay2 = (float)(int)(y2*0.5f);
    float areaA = (ax2-ax1)*(ay2-ay1);

    // IoU argmax over prev boxes (numpy first-max tie-break)
    float bi = -1.0f; int bj = 0;
    for (int j = lane; j < Np; j += 64) {
        float px1 = bp[j*5+0], py1 = bp[j*5+1], px2 = bp[j*5+2], py2 = bp[j*5+3];
        float bx1 = (float)(int)(px1*0.5f), by1 = (float)(int)(py1*0.5f);
        float bx2 = (float)(int)(px2*0.5f), by2 = (float)(int)(py2*0.5f);
        float ix1 = fmaxf(ax1,bx1), iy1 = fmaxf(ay1,by1);
        float ix2 = fminf(ax2,bx2), iy2 = fminf(ay2,by2);
        float inter = fmaxf(ix2-ix1,0.0f)*fmaxf(iy2-iy1,0.0f);
        float areaB = (bx2-bx1)*(by2-by1);
        float iou = inter/(areaA+areaB-inter);
        if (iou > bi || (iou == bi && j < bj)) { bi = iou; bj = j; }
    }
    for (int off = 32; off; off >>= 1) {
        float oi = __shfl_xor(bi, off);
        int   oj = __shfl_xor(bj, off);
        if (oi > bi || (oi == bi && oj < bj)) { bi = oi; bj = oj; }
    }
    bool m = bi > 0.0f;

    // grid-space rects for this box and its best-prev
    int gx1=(int)x1/BS, gy1=(int)y1/BS, gx2=((int)x2-1)/BS, gy2=((int)y2-1)/BS;
    float pjx1=bp[bj*5+0], pjy1=bp[bj*5+1], pjx2=bp[bj*5+2], pjy2=bp[bj*5+3], spj=bp[bj*5+4];
    int hx1=(int)pjx1/BS, hy1=(int)pjy1/BS, hx2=((int)pjx2-1)/BS, hy2=((int)pjy2-1)/BS;

    // isolation test against all grid rects
    bool bad = false;
    int NT = Nc + Np;
    for (int k = lane; k < NT; k += 64) {
        const float* q = (k < Nc) ? &bc[(size_t)k*5] : &bp[(size_t)(k-Nc)*5];
        int qx1=(int)q[0]/BS, qy1=(int)q[1]/BS, qx2=((int)q[2]-1)/BS, qy2=((int)q[3]-1)/BS;
        bool ov = (gx1<=qx2)&&(qx1<=gx2)&&(gy1<=qy2)&&(qy1<=gy2);
        if (m) ov = ov || ((hx1<=qx2)&&(qx1<=hx2)&&(hy1<=qy2)&&(qy1<=hy2));
        bool excl = (k == i) || (m && k == Nc + bj);
        bad |= (ov && !excl);
    }
    bool anybad = __any(bad);

    if (lane == 0) {
        bool big = ((int)y2 - (int)y1) >= 100;
        val_c[i] = (!anybad && big && sc >= 0.7f) ? 2.0f : 1.0f;
        int4 wr = make_int4(gx1,gy1,gx2,gy2);
        if (m) { wr.x=min(gx1,hx1); wr.y=min(gy1,hy1); wr.z=max(gx2,hx2); wr.w=max(gy2,hy2); }
        ((int4*)wrect)[i] = wr;
        bj_matched[i] = m ? bj : -1;
        float ig = 1.0f - bi;
        ((int4*)rm)[i] = make_int4((int)(x1*0.5f),(int)(y1*0.5f),(int)(x2*0.5f),(int)(y2*0.5f));
        wm[i] = ig * sc;
        ((int4*)rm)[Nc+i] = make_int4((int)(pjx1*0.5f),(int)(pjy1*0.5f),(int)(pjx2*0.5f),(int)(pjy2*0.5f));
        wm[Nc+i] = m ? ig * spj : 0.0f;
    }
}

// ---------------- K2: fused grid_ig + mask rasterization ----------------
__global__ __launch_bounds__(256) void k_gridmask(
    const float* __restrict__ bp,
    const int* __restrict__ rm, const float* __restrict__ wm,
    const int* __restrict__ wrect, const float* __restrict__ val_c,
    const int* __restrict__ bj_matched,
    int Nc, int Np, float* __restrict__ out)
{
    __shared__ int4  Lr[LMAX];
    __shared__ float Lw[LMAX];
    __shared__ unsigned int bits[64];
    __shared__ int cnt, glast;
    int tid = threadIdx.x;
    if (tid == 0) { cnt = 0; glast = -1; }
    if (tid < 64) bits[tid] = 0u;
    __syncthreads();

    // matched_prev bitmap
    for (int i = tid; i < Nc; i += 256) {
        int bj = bj_matched[i];
        if (bj >= 0) atomicOr(&bits[bj >> 5], 1u << (bj & 31));
    }
    __syncthreads();

    int bx = blockIdx.x * TILE_C;
    int by = blockIdx.y * TILE_R;

    // cull curr-derived rows (precomputed by K1)
    for (int r = tid; r < 2*Nc; r += 256) {
        int4 q = ((const int4*)rm)[r];
        float w = wm[r];
        if (w > 0.0f && q.x < bx+TILE_C && q.z > bx && q.y < by+TILE_R && q.w > by) {
            int idx = atomicAdd(&cnt, 1);
            Lr[idx] = q; Lw[idx] = w;
        }
    }
    // prev rows computed on the fly
    for (int j = tid; j < Np; j += 256) {
        bool mp = (bits[j >> 5] >> (j & 31)) & 1u;
        if (!mp) {
            float w = bp[j*5+4];
            if (w > 0.0f) {
                int4 q = make_int4((int)(bp[j*5+0]*0.5f),(int)(bp[j*5+1]*0.5f),
                                   (int)(bp[j*5+2]*0.5f),(int)(bp[j*5+3]*0.5f));
                if (q.x < bx+TILE_C && q.z > bx && q.y < by+TILE_R && q.w > by) {
                    int idx = atomicAdd(&cnt, 1);
                    Lr[idx] = q; Lw[idx] = w;
                }
            }
        }
    }

    // grid_ig: blocks 0..HG*WG-1 each own one cell
    int cell = blockIdx.y * gridDim.x + blockIdx.x;
    int last = -1;
    if (cell < HG*WG) {
        int gy = cell / WG, gx = cell % WG;
        int NT = Nc + Np;
        for (int r = tid; r < NT; r += 256) {
            int4 q; bool act;
            if (r < Nc) { q = ((const int4*)wrect)[r]; act = true; }
            else {
                int j = r - Nc;
                act = !((bits[j >> 5] >> (j & 31)) & 1u);
                q = make_int4((int)bp[j*5+0]/BS, (int)bp[j*5+1]/BS,
                              ((int)bp[j*5+2]-1)/BS, ((int)bp[j*5+3]-1)/BS);
            }
            if (act && gx >= q.x && gx <= q.z && gy >= q.y && gy <= q.w) last = r;
        }
        if (last >= 0) atomicMax(&glast, last);
    }
    __syncthreads();   // cnt + glast final

    if (cell < HG*WG && tid == 0) {
        int g = glast;
        out[(size_t)H*W + cell] = (g >= 0) ? (g < Nc ? val_c[g] : 1.0f) : 0.0f;
    }

    // per-pixel max over culled list, fused 2x2 upsample store
    int n = cnt;
    int tx = tid & 31;    // 32 col-groups * 2 cells
    int ty = tid >> 5;    // 8 row-groups * 4 rows
    int c0 = bx + tx * 2;
    int r0 = by + ty * 4;
    float mv[4][2];
    #pragma unroll
    for (int rr = 0; rr < 4; rr++) { mv[rr][0] = 0.0f; mv[rr][1] = 0.0f; }
    for (int k = 0; k < n; k++) {
        int4 q = Lr[k];          // broadcast LDS read
        float w = Lw[k];
        bool cx0 = (c0     >= q.x) && (c0     < q.z);
        bool cx1 = (c0 + 1 >= q.x) && (c0 + 1 < q.z);
        #pragma unroll
        for (int rr = 0; rr < 4; rr++) {
            int y = r0 + rr;
            bool cy = (y >= q.y) && (y < q.w);
            if (cy && cx0) mv[rr][0] = fmaxf(mv[rr][0], w);
            if (cy && cx1) mv[rr][1] = fmaxf(mv[rr][1], w);
        }
    }
    #pragma unroll
    for (int rr = 0; rr < 4; rr++) {
        int y = r0 + rr;
        float4 v = make_float4(mv[rr][0], mv[rr][0], mv[rr][1], mv[rr][1]);
        *(float4*)&out[(size_t)(2*y)     * W + 2*c0] = v;
        *(float4*)&out[(size_t)(2*y + 1) * W + 2*c0] = v;
    }
}

extern "C" void kernel_launch(void* const* d_in, const int* in_sizes, int n_in,
                              void* d_out, int out_size, void* d_ws, size_t ws_size,
                              hipStream_t stream)
{
    const float* bc = (const float*)d_in[0];
    const float* bp = (const float*)d_in[1];
    int Nc = in_sizes[0] / 5;
    int Np = in_sizes[1] / 5;
    float* out = (float*)d_out;

    int* w = (int*)d_ws;
    int* wrect      = w;          w += Nc * 4;
    float* val_c    = (float*)w;  w += Nc;
    int* bj_matched = w;          w += Nc;
    int* rm         = w;          w += 2 * Nc * 4;
    float* wm       = (float*)w;  w += 2 * Nc;

    k_match<<<Nc, 64, 0, stream>>>(bc, bp, Nc, Np, wrect, val_c, bj_matched, rm, wm);
    dim3 gmask(Ws / TILE_C, Hs / TILE_R);
    k_gridmask<<<gmask, 256, 0, stream>>>(bp, rm, wm, wrect, val_c, bj_matched, Nc, Np, out);
}